// Round 16
// baseline (224.905 us; speedup 1.0000x reference)
//
#include <hip/hip_runtime.h>

#define GN 100000
#define GE 1600000
#define GH 128
#define GOUT 64

#define NBUCK 391         // ceil(GN / 256); bucket = dst >> 8 (391 blocks ~= full 256-CU coverage)
#define BK 256            // nodes per bucket
#define BCAP 4608         // mean 4096 + 8 sigma
#define P1B 196           // pass-1 blocks
#define P1E 8192          // edges per pass-1 block (196*8192 >= GE)

// k_exp_full geometry: 1250 blocks x 16 waves x NPW nodes = 100000 exactly.
// 80 nodes/block = 5 GEMM row-tiles x 4 col-chunks = 20 units spread over 16 waves.
#define NPW 5             // nodes per wave (contiguous)
#define CAPE 110          // staged edge cap per wave (mean 80, +3.4 sigma; fallback beyond)
#define CAPW 112          // LDS slots per wave (16 B-aligned stride)

typedef _Float16 half8v __attribute__((ext_vector_type(8)));
typedef _Float16 half4v __attribute__((ext_vector_type(4)));
typedef _Float16 half2v __attribute__((ext_vector_type(2)));
typedef float floatx4 __attribute__((ext_vector_type(4)));

__device__ __forceinline__ float dot2acc(half2v a, half2v b, float c) {
#if __has_builtin(__builtin_amdgcn_fdot2)
  return __builtin_amdgcn_fdot2(a, b, c, false);
#else
  return fmaf((float)a[0], (float)b[0], fmaf((float)a[1], (float)b[1], c));
#endif
}

// ---------------- zero bucket allocators (capture-safe plain dispatch) ----------------

__global__ __launch_bounds__(512) void k_zero(int* __restrict__ gCnt) {
  gCnt[threadIdx.x] = 0;  // 512 >= NBUCK
}

// ---------------- pass 1 + prep (merged): edge place || PWL table / Wc / bc ----------------
// Blocks 0..P1B-1: fused count+place (register-cached single ei read, LDS histogram,
// one global atomicAdd per (block,bucket), scatter). Blocks P1B..P1B+9: the former
// k_prep work (PWL table, Wch = W3@Wo, bch, sentinel) -- runs CONCURRENTLY with the
// edge blocks. Dependencies: tabS/knots consumed by p2b/k_exp; Wch/bch downstream.
//
// tabS layout (BIN-MAJOR for whole-wave reads): bin b, pair P=c>>1, parity c&1:
// uint index ((b*64 + P)*2 + par); one bin row = 128 ch * 4 B = 512 B, so a wave
// reads one contiguous 512 B row -> zero LDS bank conflicts.
// Layer-1 output is rank-1 in svec: h1[d][k] = relu(svec[d]*W1[k] + b1[k]);
// t[s][c] = p_s*A[bin_s][c] + q_s*B[bin_s][c].

__global__ __launch_bounds__(1024) void p1_prep(const int* __restrict__ ei, int* __restrict__ gCnt,
                                                unsigned* __restrict__ staged,
                                                const float* __restrict__ W1, const float* __restrict__ b1,
                                                const float* __restrict__ W2, const float* __restrict__ W3,
                                                const float* __restrict__ Wo, const float* __restrict__ b3,
                                                const float* __restrict__ bo, unsigned* __restrict__ tabS,
                                                float* __restrict__ knots, _Float16* __restrict__ Wch,
                                                float* __restrict__ bch, int* __restrict__ rowStart) {
  int tid = threadIdx.x;
  int blk = blockIdx.x;
  if (blk < P1B) {
    __shared__ int cur[NBUCK];
    __shared__ int base[NBUCK];
    if (tid < NBUCK) cur[tid] = 0;
    __syncthreads();
    int e0 = blk * P1E;
    int sv[8], dv[8];
#pragma unroll
    for (int k = 0; k < 8; ++k) {
      int e = e0 + k * 1024 + tid;
      if (e < GE) {
        sv[k] = ei[e];
        dv[k] = ei[GE + e];
      } else {
        sv[k] = 0;
        dv[k] = -1;  // sentinel: skip
      }
    }
#pragma unroll
    for (int k = 0; k < 8; ++k) {
      if (dv[k] >= 0) atomicAdd(&cur[dv[k] >> 8], 1);  // LDS
    }
    __syncthreads();
    if (tid < NBUCK) {
      base[tid] = atomicAdd(&gCnt[tid], cur[tid]);  // global base for this block's run
      cur[tid] = 0;
    }
    __syncthreads();
#pragma unroll
    for (int k = 0; k < 8; ++k) {
      if (dv[k] >= 0) {
        int bb = dv[k] >> 8;
        int r = atomicAdd(&cur[bb], 1);
        int pos = base[bb] + r;
        if (pos < BCAP) staged[(size_t)bb * BCAP + pos] = ((unsigned)sv[k] << 8) | (unsigned)(dv[k] & 255);
      }
    }
  } else if (blk == P1B) {
    // PWL table build, 1024-thread strides
    __shared__ _Float16 sW2[GH * GH];  // 32 KB
    __shared__ float sW1[GH], sb1[GH], th[GH];
    __shared__ int sidx[GH];
    for (int i = tid; i < GH * GH / 4; i += 1024) {
      float4 v = ((const float4*)W2)[i];
      half4v h;
      h[0] = (_Float16)v.x; h[1] = (_Float16)v.y; h[2] = (_Float16)v.z; h[3] = (_Float16)v.w;
      ((half4v*)sW2)[i] = h;
    }
    if (tid < GH) {
      float w1 = W1[tid], bb = b1[tid];
      sW1[tid] = w1;
      sb1[tid] = bb;
      th[tid] = (w1 != 0.0f) ? (-bb / w1) : 3.0e38f;
    }
    __syncthreads();
    if (tid < GH) {
      float my = th[tid];
      int r = 0;
      for (int j = 0; j < GH; ++j) {
        float tj = th[j];
        r += (tj < my) || (tj == my && j < tid);
      }
      sidx[r] = tid;
      knots[r] = my;
    }
    __syncthreads();
    if (tid < GH) {
      int c = tid;
      // state at u = -inf: active = {W1<0} plus constants {W1==0 && b1>0}
      float A = 0.f, B = 0.f;
      for (int k = 0; k < GH; ++k) {
        float w1 = sW1[k];
        float w2 = (float)sW2[k * GH + c];
        if (w1 < 0.0f) {
          A = fmaf(w1, w2, A);
          B = fmaf(sb1[k], w2, B);
        } else if (w1 == 0.0f && sb1[k] > 0.0f) {
          B = fmaf(sb1[k], w2, B);
        }
      }
      for (int b = 0; b <= GH; ++b) {
        half2v hh;
        hh[0] = (_Float16)A;
        hh[1] = (_Float16)B;
        tabS[((b * 64 + (c >> 1)) << 1) + (c & 1)] = __builtin_bit_cast(unsigned, hh);
        if (b < GH) {
          int k = sidx[b];
          float w1 = sW1[k];
          float w2 = (float)sW2[k * GH + c];
          if (w1 > 0.0f) {            // crossing ascending: neuron turns on
            A = fmaf(w1, w2, A);
            B = fmaf(sb1[k], w2, B);
          } else if (w1 < 0.0f) {     // neuron turns off
            A = fmaf(-w1, w2, A);
            B = fmaf(-sb1[k], w2, B);
          }
        }
      }
    }
  } else if (blk <= P1B + 8) {
    int idx = (blk - P1B - 1) * 1024 + tid;  // 0..8191
    int k = idx >> 6, c = idx & 63;
    float s = 0.f;
#pragma unroll 8
    for (int j = 0; j < GH; ++j) s = fmaf(W3[k * GH + j], Wo[j * GOUT + c], s);
    Wch[idx] = (_Float16)s;
  } else {
    if (tid < GOUT) {
      float s = bo[tid];
      for (int j = 0; j < GH; ++j) s = fmaf(b3[j], Wo[j * GOUT + tid], s);
      bch[tid] = s;
    }
    if (tid == 1023) rowStart[GN] = GE;  // sentinel
  }
}

// ---------------- pass 2a: per-bucket hist/scan -> rowStart, dinv, xs ----------------

__global__ __launch_bounds__(1024) void p2a_build(const unsigned* __restrict__ staged,
                                                  const int* __restrict__ gCnt, const float* __restrict__ x,
                                                  float* __restrict__ dinv, float* __restrict__ xs,
                                                  int* __restrict__ rowStart) {
  __shared__ int cntL[BK];
  __shared__ int wsum[4];
  __shared__ int totL[NBUCK];
  __shared__ int baseSh;
  int b = blockIdx.x;
  int tid = threadIdx.x;
  if (tid < NBUCK) totL[tid] = gCnt[tid];
  if (tid < BK) cntL[tid] = 0;
  __syncthreads();
  if (tid == 0) {
    int s = 0;
    for (int j = 0; j < b; ++j) s += totL[j];
    baseSh = s;
  }
  int n = totL[b];
  if (n > BCAP) n = BCAP;
  __syncthreads();
  int base = baseSh;
  const unsigned* st = staged + (size_t)b * BCAP;
  for (int i = tid; i < n; i += 1024) atomicAdd(&cntL[st[i] & 255], 1);
  __syncthreads();
  int v = (tid < BK) ? cntL[tid] : 0;
  int lane = tid & 63, w = tid >> 6;
  int inc = v;
#pragma unroll
  for (int off = 1; off < 64; off <<= 1) {
    int u = __shfl_up(inc, off, 64);
    if (lane >= off) inc += u;
  }
  if (tid < BK && lane == 63) wsum[w] = inc;
  __syncthreads();
  if (tid < BK) {
    int woff = 0;
    for (int i = 0; i < w; ++i) woff += wsum[i];
    int ex = inc - v + woff;
    int node = b * BK + tid;
    if (node < GN) {
      rowStart[node] = base + ex;
      float dv = rsqrtf((float)(v + 1));
      dinv[node] = dv;
      xs[node] = x[node] * dv;
    }
  }
}

// ---------------- pass 2b: scatter csr + FUSED layer-1 aggregate + (p,q,bin*512) ----------------

__global__ __launch_bounds__(1024) void p2b_scatter(const unsigned* __restrict__ staged,
                                                    const int* __restrict__ gCnt, const float* __restrict__ xs,
                                                    const float* __restrict__ dinv, const int* __restrict__ rowStart,
                                                    const float* __restrict__ knots, int* __restrict__ csr,
                                                    uint2* __restrict__ pqb) {
  __shared__ int curL[BK];
  __shared__ float accL[BK];
  __shared__ float kn[GH];
  int b = blockIdx.x;
  int tid = threadIdx.x;
  if (tid < GH) kn[tid] = knots[tid];
  int base = rowStart[b * BK];  // bucket base == first node's rowStart (b*BK < GN always)
  int node = b * BK + tid;      // valid for tid < BK
  if (tid < BK) {
    curL[tid] = (node < GN) ? (rowStart[node] - base) : 0;
    accL[tid] = 0.f;
  }
  int n = gCnt[b];
  if (n > BCAP) n = BCAP;
  __syncthreads();
  const unsigned* st = staged + (size_t)b * BCAP;
  int i = tid;
  for (; i + 3072 < n; i += 4096) {  // 4-batch: keep 8 loads in flight
    unsigned u0 = st[i], u1 = st[i + 1024], u2 = st[i + 2048], u3 = st[i + 3072];
    float x0 = xs[u0 >> 8], x1 = xs[u1 >> 8], x2 = xs[u2 >> 8], x3 = xs[u3 >> 8];
    int p0 = atomicAdd(&curL[u0 & 255], 1);
    csr[base + p0] = (int)(u0 >> 8);
    atomicAdd(&accL[u0 & 255], x0);
    int p1 = atomicAdd(&curL[u1 & 255], 1);
    csr[base + p1] = (int)(u1 >> 8);
    atomicAdd(&accL[u1 & 255], x1);
    int p2 = atomicAdd(&curL[u2 & 255], 1);
    csr[base + p2] = (int)(u2 >> 8);
    atomicAdd(&accL[u2 & 255], x2);
    int p3 = atomicAdd(&curL[u3 & 255], 1);
    csr[base + p3] = (int)(u3 >> 8);
    atomicAdd(&accL[u3 & 255], x3);
  }
  for (; i < n; i += 1024) {
    unsigned u = st[i];
    float xv = xs[u >> 8];
    int p = atomicAdd(&curL[u & 255], 1);
    csr[base + p] = (int)(u >> 8);
    atomicAdd(&accL[u & 255], xv);
  }
  __syncthreads();
  if (tid < BK && node < GN) {
    float q = dinv[node];
    float u = (accL[tid] + xs[node]) * q;  // svec (self loop included)
    int lo = 0;                            // rank = #knots < u, in [0,128]
#pragma unroll
    for (int s = 64; s > 0; s >>= 1)
      if (kn[lo + s - 1] < u) lo += s;
    if (lo < GH && kn[lo] < u) ++lo;  // final correction step
    half2v ph;
    ph[0] = (_Float16)(u * q);  // p
    ph[1] = (_Float16)q;        // q
    pqb[node] = make_uint2(__builtin_bit_cast(unsigned, ph), (unsigned)(lo << 9));
  }
}

// ---------------- layer 2 + GEMM (fused): pair-split expand, then 20-unit MFMA spread ----------------
// 1250 blocks x 1024 threads (16 waves) x NPW=5 nodes = 100000 exactly. Main loop as R12
// (pair-split, 2 blocks/CU, scalar control plane). GEMM tail: 80x64 output = 5 row-tiles
// x 4 col-chunks = 20 independent units of 4 chained MFMAs, spread over ALL 16 waves
// (waves 0..3 take a second unit) -- R15's 5-wave/16-MFMA-chain tail was ~14 us with
// 11 idle waves; longest chain now 8 MFMAs. sTab reused as transposed Wc (17.4 KB);
// LDS total unchanged 80384 B -> 2 blocks/CU retained.

__global__ __launch_bounds__(1024, 8) void k_exp_full(const uint2* __restrict__ pqb, const int* __restrict__ csr,
                                                      const int* __restrict__ rowStart, const unsigned* __restrict__ tabS,
                                                      const float* __restrict__ dinv, const float* __restrict__ b2,
                                                      const _Float16* __restrict__ Wch, _Float16* __restrict__ h2out,
                                                      _Float16* __restrict__ t3out) {
  __shared__ __align__(16) uint2 sTab[129 * 64];   // 66048 B; reused as WtL after main loop
  __shared__ __align__(16) uint2 sBuf[16 * CAPW];  // 14336 B, per-wave edge streams
  int tid = threadIdx.x;
  // cooperative table load: 4128 x 16 B, straight copy (global layout == LDS layout)
  {
    const uint4* tg = (const uint4*)tabS;
    uint4* td = (uint4*)sTab;
    for (int i = tid; i < 4128; i += 1024) td[i] = tg[i];
  }
  int lane = tid & 63, wv = tid >> 6;
  int h = lane >> 5;   // edge-of-pair slot
  int l = lane & 31;   // 4-channel group
  int wid = blockIdx.x * 16 + wv;
  int n0 = wid * NPW;                       // 1250*16*5 = 100000 exactly, no bounds
  int wl = lane <= NPW ? lane : NPW;
  int rsv = rowStart[n0 + wl];              // lane-indexed window; rowStart[GN]=GE sentinel
  int eBeg = __builtin_amdgcn_readlane(rsv, 0);         // SGPR
  int eTot = __builtin_amdgcn_readlane(rsv, NPW) - eBeg;
  int nE = eTot < CAPE ? eTot : CAPE;                   // SGPR
  int eClamp = eBeg < GE - 1 ? eBeg : GE - 1;           // in-bounds dummy index
  // breadth-first staging: both csr chunk loads in flight, then both gathers
  int srcv[2];
#pragma unroll
  for (int c = 0; c < 2; ++c) {
    int i = c * 64 + lane;
    srcv[c] = csr[i < nE ? eBeg + i : eClamp];  // clamp keeps address valid; masked at write
  }
  uint2 pv[2];
#pragma unroll
  for (int c = 0; c < 2; ++c) pv[c] = pqb[srcv[c]];
  uint2* bw = sBuf + wv * CAPW;
#pragma unroll
  for (int c = 0; c < 2; ++c) {
    int i = c * 64 + lane;
    if (i < nE) bw[i] = pv[c];
  }
  __syncthreads();

  {
    const char* tbl16 = (const char*)sTab + l * 16;  // this lane's 4-channel column
    const char* bwB = (const char*)bw;
    float4 bb4 = ((const float4*)b2)[l];             // bias for channels 4l..4l+3

    float a0 = 0.f, a1 = 0.f, a2 = 0.f, a3 = 0.f;
    auto fdot4 = [&](uint4 t, unsigned pm) {
      half2v ph = __builtin_bit_cast(half2v, pm);
      a0 = dot2acc(__builtin_bit_cast(half2v, t.x), ph, a0);
      a1 = dot2acc(__builtin_bit_cast(half2v, t.y), ph, a1);
      a2 = dot2acc(__builtin_bit_cast(half2v, t.z), ph, a2);
      a3 = dot2acc(__builtin_bit_cast(half2v, t.w), ph, a3);
    };
    auto procM = [&](uint2 v) {  // single edge; half 1 contributes exactly 0
      unsigned pm = (h == 0) ? v.x : 0u;
      uint4 t = *(const uint4*)(tbl16 + v.y);
      fdot4(t, pm);
    };

    int sB = 0;  // SGPR: node's begin (stream-local)
    for (int d = 0; d < NPW; ++d) {
      int sE = __builtin_amdgcn_readlane(rsv, d + 1) - eBeg;  // SGPR: node's end
      a0 = 0.f; a1 = 0.f; a2 = 0.f; a3 = 0.f;
      int lim = sE < nE ? sE : nE;
      int j = sB;
      for (; j + 8 <= lim; j += 8) {  // 4 pairs in flight; scalar loop bounds
        const char* p = bwB + (size_t)(j + h) * 8;  // half h reads edges j+h, j+2+h, ...
        uint2 v0 = *(const uint2*)(p);
        uint2 v1 = *(const uint2*)(p + 16);
        uint2 v2 = *(const uint2*)(p + 32);
        uint2 v3 = *(const uint2*)(p + 48);
        uint4 t0 = *(const uint4*)(tbl16 + v0.y);
        uint4 t1 = *(const uint4*)(tbl16 + v1.y);
        uint4 t2 = *(const uint4*)(tbl16 + v2.y);
        uint4 t3 = *(const uint4*)(tbl16 + v3.y);
        fdot4(t0, v0.x);
        fdot4(t1, v1.x);
        fdot4(t2, v2.x);
        fdot4(t3, v3.x);
      }
      for (; j + 2 <= lim; j += 2) {  // pair remainder
        uint2 v = *(const uint2*)(bwB + (size_t)(j + h) * 8);
        uint4 t = *(const uint4*)(tbl16 + v.y);
        fdot4(t, v.x);
      }
      if (j < lim) procM(*(const uint2*)(bwB + (size_t)j * 8));  // odd last edge
      // overflow fallback (rows past CAPE): wave-uniform global loads; ~never taken
      for (int j2 = (sB > nE ? sB : nE); j2 < sE; ++j2) {
        int s2 = csr[eBeg + j2];
        procM(pqb[s2]);
      }
      procM(pqb[n0 + d]);  // self loop (wave-uniform load; 1 per ~80 edges)
      // cross-half reduce: halves hold disjoint edge subsets of the SAME channels
      a0 += __shfl_xor(a0, 32);
      a1 += __shfl_xor(a1, 32);
      a2 += __shfl_xor(a2, 32);
      a3 += __shfl_xor(a3, 32);
      if (h == 0) {
        float dvv = dinv[n0 + d];
        float r0 = fmaxf(fmaf(a0, dvv, bb4.x), 0.f);
        float r1 = fmaxf(fmaf(a1, dvv, bb4.y), 0.f);
        float r2 = fmaxf(fmaf(a2, dvv, bb4.z), 0.f);
        float r3 = fmaxf(fmaf(a3, dvv, bb4.w), 0.f);
        half2v o01, o23;
        o01[0] = (_Float16)r0; o01[1] = (_Float16)r1;
        o23[0] = (_Float16)r2; o23[1] = (_Float16)r3;
        uint2 ov;
        ov.x = __builtin_bit_cast(unsigned, o01);
        ov.y = __builtin_bit_cast(unsigned, o23);
        ((uint2*)h2out)[(size_t)(n0 + d) * 32 + l] = ov;  // 32 lanes x 8 B = 256 B row
      }
      sB = sE;
    }
  }

  // ---- fused GEMM, 20 units over 16 waves: unit u = (tile u/4, colchunk u%4) ----
  constexpr int WS = 136;
  _Float16* WtL = (_Float16*)sTab;  // 64*136*2 = 17408 B <= 66048 B
  __syncthreads();                  // main-loop writes/readers done; sTab dead
  for (int i = tid; i < GH * GOUT; i += 1024) {
    int k = i >> 6, n = i & 63;
    WtL[n * WS + k] = Wch[i];
  }
  __syncthreads();
  {
    int m = lane & 15, q = lane >> 4;
    auto gemmUnit = [&](int t, int c) {
      int row = blockIdx.x * 80 + t * 16 + m;  // row's h2 was written by THIS block
      const _Float16* arow = h2out + (size_t)row * GH + q * 8;
      floatx4 acc = {0.0f, 0.0f, 0.0f, 0.0f};
#pragma unroll
      for (int ks = 0; ks < 4; ++ks) {
        half8v af = *(const half8v*)(arow + ks * 32);
        half8v wf = *(const half8v*)(&WtL[(c * 16 + m) * WS + ks * 32 + q * 8]);
        acc = __builtin_amdgcn_mfma_f32_16x16x32_f16(wf, af, acc, 0, 0, 0);
      }
      float sc = dinv[row];
      half4v hv;
#pragma unroll
      for (int j = 0; j < 4; ++j) hv[j] = (_Float16)(acc[j] * sc);
      *(half4v*)(t3out + (size_t)row * GOUT + c * 16 + q * 4) = hv;
    };
    gemmUnit(wv >> 2, wv & 3);         // units 0..15
    if (wv < 4) gemmUnit(4, wv);       // units 16..19 (tile 4)
  }
}

// ---------------- layer 3 + head: 4 nodes/wave, uint2 row segments, depth-2 prefetch ----------------

__global__ __launch_bounds__(256) void k_agg64(const _Float16* __restrict__ ht, const int* __restrict__ rowStart,
                                               const int* __restrict__ csr, const float* __restrict__ dinv,
                                               const float* __restrict__ bias, float* __restrict__ out) {
  int tid = threadIdx.x;
  int lane = tid & 63;
  int wave = (blockIdx.x << 2) + (tid >> 6);
  int g = lane >> 4;  // node slot
  int l = lane & 15;  // uint2 segment (4 channels)
  int d = (wave << 2) + g;  // 6250*4*4 = 100000 exactly
  const uint2* h2p = (const uint2*)ht;  // row = 16 uint2
  float ax = 0.f, ay = 0.f, az = 0.f, aw = 0.f;
  auto acc4 = [&](uint2 r) {
    half2v lo = __builtin_bit_cast(half2v, r.x);
    half2v hi = __builtin_bit_cast(half2v, r.y);
    ax += (float)lo[0];
    ay += (float)lo[1];
    az += (float)hi[0];
    aw += (float)hi[1];
  };
  acc4(h2p[(size_t)d * 16 + l]);  // self loop
  int e = rowStart[d];
  int en = rowStart[d + 1];
  uint2 rA0, rA1, rA2, rA3, rB0, rB1, rB2, rB3;
  bool hA = (e + 4 <= en);
  if (hA) {
    int s0 = csr[e], s1 = csr[e + 1], s2 = csr[e + 2], s3 = csr[e + 3];
    rA0 = h2p[(size_t)s0 * 16 + l]; rA1 = h2p[(size_t)s1 * 16 + l];
    rA2 = h2p[(size_t)s2 * 16 + l]; rA3 = h2p[(size_t)s3 * 16 + l];
  }
  bool hB = (e + 8 <= en);
  if (hB) {
    int s0 = csr[e + 4], s1 = csr[e + 5], s2 = csr[e + 6], s3 = csr[e + 7];
    rB0 = h2p[(size_t)s0 * 16 + l]; rB1 = h2p[(size_t)s1 * 16 + l];
    rB2 = h2p[(size_t)s2 * 16 + l]; rB3 = h2p[(size_t)s3 * 16 + l];
  }
  while (hA) {
    bool hC = (e + 12 <= en);
    uint2 rC0, rC1, rC2, rC3;
    if (hC) {
      int n0 = csr[e + 8], n1 = csr[e + 9], n2 = csr[e + 10], n3 = csr[e + 11];
      rC0 = h2p[(size_t)n0 * 16 + l]; rC1 = h2p[(size_t)n1 * 16 + l];
      rC2 = h2p[(size_t)n2 * 16 + l]; rC3 = h2p[(size_t)n3 * 16 + l];
    }
    acc4(rA0); acc4(rA1); acc4(rA2); acc4(rA3);
    rA0 = rB0; rA1 = rB1; rA2 = rB2; rA3 = rB3;
    rB0 = rC0; rB1 = rC1; rB2 = rC2; rB3 = rC3;
    e += 4;
    hA = hB;
    hB = hC;
  }
  for (; e < en; ++e) acc4(h2p[(size_t)csr[e] * 16 + l]);
  float dv = dinv[d];
  float4 bb = ((const float4*)bias)[l];
  float4 o;
  o.x = fmaf(ax, dv, bb.x);
  o.y = fmaf(ay, dv, bb.y);
  o.z = fmaf(az, dv, bb.z);
  o.w = fmaf(aw, dv, bb.w);
  ((float4*)out)[(size_t)d * 16 + l] = o;
}

// ---------------- host ----------------

extern "C" void kernel_launch(void* const* d_in, const int* in_sizes, int n_in,
                              void* d_out, int out_size, void* d_ws, size_t ws_size,
                              hipStream_t stream) {
  const float* x  = (const float*)d_in[0];
  const int*   ei = (const int*)d_in[1];
  const float* W1 = (const float*)d_in[2];
  const float* b1 = (const float*)d_in[3];
  const float* W2 = (const float*)d_in[4];
  const float* b2 = (const float*)d_in[5];
  const float* W3 = (const float*)d_in[6];
  const float* b3 = (const float*)d_in[7];
  const float* Wo = (const float*)d_in[8];
  const float* bo = (const float*)d_in[9];
  float* out = (float*)d_out;

  char* ws = (char*)d_ws;
  size_t off = 0;
  auto alloc = [&](size_t bytes) -> char* {
    off = (off + 255) & ~(size_t)255;
    char* p = ws + off;
    off += bytes;
    return p;
  };
  float*     dinv      = (float*)alloc((size_t)GN * 4);
  float*     xs        = (float*)alloc((size_t)GN * 4);
  int*       rowStart  = (int*)alloc((size_t)(GN + 1) * 4);
  int*       gCnt      = (int*)alloc((size_t)512 * 4);
  int*       csr       = (int*)alloc((size_t)GE * 4);
  unsigned*  tabS      = (unsigned*)alloc((size_t)129 * 128 * 4);  // 66 KB, bin-major
  float*     knots     = (float*)alloc((size_t)GH * 4);
  _Float16*  Wch       = (_Float16*)alloc((size_t)GH * GOUT * 2);
  float*     bch       = (float*)alloc((size_t)GOUT * 4);
  uint2*     pqb       = (uint2*)alloc((size_t)GN * 8);
  _Float16*  bufA      = (_Float16*)alloc((size_t)GN * GH * 2);   // h2 (aliases staged)
  _Float16*  bufB      = (_Float16*)alloc((size_t)GN * GOUT * 2); // t3
  unsigned*  staged    = (unsigned*)bufA;  // 7.21 MB, dead before k_exp_full writes bufA
  (void)ws_size; (void)in_sizes; (void)n_in; (void)out_size;

  // zero bucket allocators (plain dispatch; capture-safe), then merged pass1+prep:
  // edge count/place runs CONCURRENTLY with PWL table / Wch / bch generation.
  k_zero<<<1, 512, 0, stream>>>(gCnt);
  p1_prep<<<P1B + 10, 1024, 0, stream>>>(ei, gCnt, staged, W1, b1, W2, W3, Wo, b3, bo,
                                         tabS, knots, Wch, bch, rowStart);

  // CSR build (391 buckets of 256 nodes -> full-GPU grids): hist/scan -> scatter+layer1
  p2a_build<<<NBUCK, 1024, 0, stream>>>(staged, gCnt, x, dinv, xs, rowStart);
  p2b_scatter<<<NBUCK, 1024, 0, stream>>>(staged, gCnt, xs, dinv, rowStart, knots, csr, pqb);

  // layer 2 + layer-3 GEMM fused: expand (pair-split, 2 blocks/CU), 20-unit MFMA spread
  k_exp_full<<<1250, 1024, 0, stream>>>(pqb, csr, rowStart, tabS, dinv, b2, Wch, bufA, bufB);

  // head: 4 nodes/wave uint2 aggregate -> fp32 out
  k_agg64<<<6250, 256, 0, stream>>>(bufB, rowStart, csr, dinv, bch, out);
}

// Round 17
// 216.140 us; speedup vs baseline: 1.0406x; 1.0406x over previous
//
#include <hip/hip_runtime.h>

#define GN 100000
#define GE 1600000
#define GH 128
#define GOUT 64

#define NBUCK 391         // ceil(GN / 256); bucket = dst >> 8 (391 blocks ~= full 256-CU coverage)
#define BK 256            // nodes per bucket
#define BCAP 4608         // mean 4096 + 8 sigma
#define P1B 196           // pass-1 blocks
#define P1E 8192          // edges per pass-1 block (196*8192 >= GE)

// k_exp_full geometry: 1250 blocks x 16 waves x NPW nodes = 100000 exactly.
// 80 nodes/block = exactly 5 GEMM tiles of 16 rows -> gemm fused into the same block.
#define NPW 5             // nodes per wave (contiguous)
#define CAPE 110          // staged edge cap per wave (mean 80, +3.4 sigma; fallback beyond)
#define CAPW 112          // LDS slots per wave (16 B-aligned stride)

typedef _Float16 half8v __attribute__((ext_vector_type(8)));
typedef _Float16 half4v __attribute__((ext_vector_type(4)));
typedef _Float16 half2v __attribute__((ext_vector_type(2)));
typedef float floatx4 __attribute__((ext_vector_type(4)));

__device__ __forceinline__ float dot2acc(half2v a, half2v b, float c) {
#if __has_builtin(__builtin_amdgcn_fdot2)
  return __builtin_amdgcn_fdot2(a, b, c, false);
#else
  return fmaf((float)a[0], (float)b[0], fmaf((float)a[1], (float)b[1], c));
#endif
}

// ---------------- zero bucket allocators (capture-safe plain dispatch) ----------------

__global__ __launch_bounds__(512) void k_zero(int* __restrict__ gCnt) {
  gCnt[threadIdx.x] = 0;  // 512 >= NBUCK
}

// ---------------- pass 1 + prep (merged): edge place || PWL table / Wc / bc ----------------
// Blocks 0..P1B-1: fused count+place (register-cached single ei read, LDS histogram,
// one global atomicAdd per (block,bucket), scatter). Blocks P1B..P1B+9: the former
// k_prep work (PWL table, Wch = W3@Wo, bch, sentinel) -- runs CONCURRENTLY with the
// edge blocks. Dependencies: tabS/knots consumed by p2b/k_exp; Wch/bch downstream.
//
// tabS layout (BIN-MAJOR for whole-wave reads): bin b, pair P=c>>1, parity c&1:
// uint index ((b*64 + P)*2 + par); one bin row = 128 ch * 4 B = 512 B, so a wave
// reads one contiguous 512 B row -> zero LDS bank conflicts.
// Layer-1 output is rank-1 in svec: h1[d][k] = relu(svec[d]*W1[k] + b1[k]);
// t[s][c] = p_s*A[bin_s][c] + q_s*B[bin_s][c].

__global__ __launch_bounds__(1024) void p1_prep(const int* __restrict__ ei, int* __restrict__ gCnt,
                                                unsigned* __restrict__ staged,
                                                const float* __restrict__ W1, const float* __restrict__ b1,
                                                const float* __restrict__ W2, const float* __restrict__ W3,
                                                const float* __restrict__ Wo, const float* __restrict__ b3,
                                                const float* __restrict__ bo, unsigned* __restrict__ tabS,
                                                float* __restrict__ knots, _Float16* __restrict__ Wch,
                                                float* __restrict__ bch, int* __restrict__ rowStart) {
  int tid = threadIdx.x;
  int blk = blockIdx.x;
  if (blk < P1B) {
    __shared__ int cur[NBUCK];
    __shared__ int base[NBUCK];
    if (tid < NBUCK) cur[tid] = 0;
    __syncthreads();
    int e0 = blk * P1E;
    int sv[8], dv[8];
#pragma unroll
    for (int k = 0; k < 8; ++k) {
      int e = e0 + k * 1024 + tid;
      if (e < GE) {
        sv[k] = ei[e];
        dv[k] = ei[GE + e];
      } else {
        sv[k] = 0;
        dv[k] = -1;  // sentinel: skip
      }
    }
#pragma unroll
    for (int k = 0; k < 8; ++k) {
      if (dv[k] >= 0) atomicAdd(&cur[dv[k] >> 8], 1);  // LDS
    }
    __syncthreads();
    if (tid < NBUCK) {
      base[tid] = atomicAdd(&gCnt[tid], cur[tid]);  // global base for this block's run
      cur[tid] = 0;
    }
    __syncthreads();
#pragma unroll
    for (int k = 0; k < 8; ++k) {
      if (dv[k] >= 0) {
        int bb = dv[k] >> 8;
        int r = atomicAdd(&cur[bb], 1);
        int pos = base[bb] + r;
        if (pos < BCAP) staged[(size_t)bb * BCAP + pos] = ((unsigned)sv[k] << 8) | (unsigned)(dv[k] & 255);
      }
    }
  } else if (blk == P1B) {
    // PWL table build, 1024-thread strides
    __shared__ _Float16 sW2[GH * GH];  // 32 KB
    __shared__ float sW1[GH], sb1[GH], th[GH];
    __shared__ int sidx[GH];
    for (int i = tid; i < GH * GH / 4; i += 1024) {
      float4 v = ((const float4*)W2)[i];
      half4v h;
      h[0] = (_Float16)v.x; h[1] = (_Float16)v.y; h[2] = (_Float16)v.z; h[3] = (_Float16)v.w;
      ((half4v*)sW2)[i] = h;
    }
    if (tid < GH) {
      float w1 = W1[tid], bb = b1[tid];
      sW1[tid] = w1;
      sb1[tid] = bb;
      th[tid] = (w1 != 0.0f) ? (-bb / w1) : 3.0e38f;
    }
    __syncthreads();
    if (tid < GH) {
      float my = th[tid];
      int r = 0;
      for (int j = 0; j < GH; ++j) {
        float tj = th[j];
        r += (tj < my) || (tj == my && j < tid);
      }
      sidx[r] = tid;
      knots[r] = my;
    }
    __syncthreads();
    if (tid < GH) {
      int c = tid;
      // state at u = -inf: active = {W1<0} plus constants {W1==0 && b1>0}
      float A = 0.f, B = 0.f;
      for (int k = 0; k < GH; ++k) {
        float w1 = sW1[k];
        float w2 = (float)sW2[k * GH + c];
        if (w1 < 0.0f) {
          A = fmaf(w1, w2, A);
          B = fmaf(sb1[k], w2, B);
        } else if (w1 == 0.0f && sb1[k] > 0.0f) {
          B = fmaf(sb1[k], w2, B);
        }
      }
      for (int b = 0; b <= GH; ++b) {
        half2v hh;
        hh[0] = (_Float16)A;
        hh[1] = (_Float16)B;
        tabS[((b * 64 + (c >> 1)) << 1) + (c & 1)] = __builtin_bit_cast(unsigned, hh);
        if (b < GH) {
          int k = sidx[b];
          float w1 = sW1[k];
          float w2 = (float)sW2[k * GH + c];
          if (w1 > 0.0f) {            // crossing ascending: neuron turns on
            A = fmaf(w1, w2, A);
            B = fmaf(sb1[k], w2, B);
          } else if (w1 < 0.0f) {     // neuron turns off
            A = fmaf(-w1, w2, A);
            B = fmaf(-sb1[k], w2, B);
          }
        }
      }
    }
  } else if (blk <= P1B + 8) {
    int idx = (blk - P1B - 1) * 1024 + tid;  // 0..8191
    int k = idx >> 6, c = idx & 63;
    float s = 0.f;
#pragma unroll 8
    for (int j = 0; j < GH; ++j) s = fmaf(W3[k * GH + j], Wo[j * GOUT + c], s);
    Wch[idx] = (_Float16)s;
  } else {
    if (tid < GOUT) {
      float s = bo[tid];
      for (int j = 0; j < GH; ++j) s = fmaf(b3[j], Wo[j * GOUT + tid], s);
      bch[tid] = s;
    }
    if (tid == 1023) rowStart[GN] = GE;  // sentinel
  }
}

// ---------------- pass 2a: per-bucket hist/scan -> rowStart, dinv, xs ----------------

__global__ __launch_bounds__(1024) void p2a_build(const unsigned* __restrict__ staged,
                                                  const int* __restrict__ gCnt, const float* __restrict__ x,
                                                  float* __restrict__ dinv, float* __restrict__ xs,
                                                  int* __restrict__ rowStart) {
  __shared__ int cntL[BK];
  __shared__ int wsum[4];
  __shared__ int totL[NBUCK];
  __shared__ int baseSh;
  int b = blockIdx.x;
  int tid = threadIdx.x;
  if (tid < NBUCK) totL[tid] = gCnt[tid];
  if (tid < BK) cntL[tid] = 0;
  __syncthreads();
  if (tid == 0) {
    int s = 0;
    for (int j = 0; j < b; ++j) s += totL[j];
    baseSh = s;
  }
  int n = totL[b];
  if (n > BCAP) n = BCAP;
  __syncthreads();
  int base = baseSh;
  const unsigned* st = staged + (size_t)b * BCAP;
  for (int i = tid; i < n; i += 1024) atomicAdd(&cntL[st[i] & 255], 1);
  __syncthreads();
  int v = (tid < BK) ? cntL[tid] : 0;
  int lane = tid & 63, w = tid >> 6;
  int inc = v;
#pragma unroll
  for (int off = 1; off < 64; off <<= 1) {
    int u = __shfl_up(inc, off, 64);
    if (lane >= off) inc += u;
  }
  if (tid < BK && lane == 63) wsum[w] = inc;
  __syncthreads();
  if (tid < BK) {
    int woff = 0;
    for (int i = 0; i < w; ++i) woff += wsum[i];
    int ex = inc - v + woff;
    int node = b * BK + tid;
    if (node < GN) {
      rowStart[node] = base + ex;
      float dv = rsqrtf((float)(v + 1));
      dinv[node] = dv;
      xs[node] = x[node] * dv;
    }
  }
}

// ---------------- pass 2b: scatter csr + FUSED layer-1 aggregate + (p,q,bin*512) ----------------

__global__ __launch_bounds__(1024) void p2b_scatter(const unsigned* __restrict__ staged,
                                                    const int* __restrict__ gCnt, const float* __restrict__ xs,
                                                    const float* __restrict__ dinv, const int* __restrict__ rowStart,
                                                    const float* __restrict__ knots, int* __restrict__ csr,
                                                    uint2* __restrict__ pqb) {
  __shared__ int curL[BK];
  __shared__ float accL[BK];
  __shared__ float kn[GH];
  int b = blockIdx.x;
  int tid = threadIdx.x;
  if (tid < GH) kn[tid] = knots[tid];
  int base = rowStart[b * BK];  // bucket base == first node's rowStart (b*BK < GN always)
  int node = b * BK + tid;      // valid for tid < BK
  if (tid < BK) {
    curL[tid] = (node < GN) ? (rowStart[node] - base) : 0;
    accL[tid] = 0.f;
  }
  int n = gCnt[b];
  if (n > BCAP) n = BCAP;
  __syncthreads();
  const unsigned* st = staged + (size_t)b * BCAP;
  int i = tid;
  for (; i + 3072 < n; i += 4096) {  // 4-batch: keep 8 loads in flight
    unsigned u0 = st[i], u1 = st[i + 1024], u2 = st[i + 2048], u3 = st[i + 3072];
    float x0 = xs[u0 >> 8], x1 = xs[u1 >> 8], x2 = xs[u2 >> 8], x3 = xs[u3 >> 8];
    int p0 = atomicAdd(&curL[u0 & 255], 1);
    csr[base + p0] = (int)(u0 >> 8);
    atomicAdd(&accL[u0 & 255], x0);
    int p1 = atomicAdd(&curL[u1 & 255], 1);
    csr[base + p1] = (int)(u1 >> 8);
    atomicAdd(&accL[u1 & 255], x1);
    int p2 = atomicAdd(&curL[u2 & 255], 1);
    csr[base + p2] = (int)(u2 >> 8);
    atomicAdd(&accL[u2 & 255], x2);
    int p3 = atomicAdd(&curL[u3 & 255], 1);
    csr[base + p3] = (int)(u3 >> 8);
    atomicAdd(&accL[u3 & 255], x3);
  }
  for (; i < n; i += 1024) {
    unsigned u = st[i];
    float xv = xs[u >> 8];
    int p = atomicAdd(&curL[u & 255], 1);
    csr[base + p] = (int)(u >> 8);
    atomicAdd(&accL[u & 255], xv);
  }
  __syncthreads();
  if (tid < BK && node < GN) {
    float q = dinv[node];
    float u = (accL[tid] + xs[node]) * q;  // svec (self loop included)
    int lo = 0;                            // rank = #knots < u, in [0,128]
#pragma unroll
    for (int s = 64; s > 0; s >>= 1)
      if (kn[lo + s - 1] < u) lo += s;
    if (lo < GH && kn[lo] < u) ++lo;  // final correction step
    half2v ph;
    ph[0] = (_Float16)(u * q);  // p
    ph[1] = (_Float16)q;        // q
    pqb[node] = make_uint2(__builtin_bit_cast(unsigned, ph), (unsigned)(lo << 9));
  }
}

// ---------------- layer 2 + GEMM (fused): pair-split expand, then per-block MFMA ----------------
// 1250 blocks x 1024 threads (16 waves) x NPW=5 nodes = 100000 exactly. Main loop as R12
// (pair-split, 2 blocks/CU, scalar control plane). A block's 80 nodes = exactly 5 GEMM
// tiles of 16 rows, all of whose h2 rows THIS block just wrote -> after __syncthreads()
// (orders the block's global writes for its own reads), waves 0..4 each run one 16x64
// fp16-MFMA tile: t = (h2 @ Wc) * dinv[row] -> bufB. af loaded ONCE per row, reused
// across all 4 col-chunks (R16 showed per-unit reload quadruples A-traffic and loses).
// The dead sTab LDS is reused for the transposed Wc tile (17.4 KB <= 66 KB; total LDS
// unchanged 80384 B -> 2 blocks/CU retained).

__global__ __launch_bounds__(1024, 8) void k_exp_full(const uint2* __restrict__ pqb, const int* __restrict__ csr,
                                                      const int* __restrict__ rowStart, const unsigned* __restrict__ tabS,
                                                      const float* __restrict__ dinv, const float* __restrict__ b2,
                                                      const _Float16* __restrict__ Wch, _Float16* __restrict__ h2out,
                                                      _Float16* __restrict__ t3out) {
  __shared__ __align__(16) uint2 sTab[129 * 64];   // 66048 B; reused as WtL after main loop
  __shared__ __align__(16) uint2 sBuf[16 * CAPW];  // 14336 B, per-wave edge streams
  int tid = threadIdx.x;
  // cooperative table load: 4128 x 16 B, straight copy (global layout == LDS layout)
  {
    const uint4* tg = (const uint4*)tabS;
    uint4* td = (uint4*)sTab;
    for (int i = tid; i < 4128; i += 1024) td[i] = tg[i];
  }
  int lane = tid & 63, wv = tid >> 6;
  int h = lane >> 5;   // edge-of-pair slot
  int l = lane & 31;   // 4-channel group
  int wid = blockIdx.x * 16 + wv;
  int n0 = wid * NPW;                       // 1250*16*5 = 100000 exactly, no bounds
  int wl = lane <= NPW ? lane : NPW;
  int rsv = rowStart[n0 + wl];              // lane-indexed window; rowStart[GN]=GE sentinel
  int eBeg = __builtin_amdgcn_readlane(rsv, 0);         // SGPR
  int eTot = __builtin_amdgcn_readlane(rsv, NPW) - eBeg;
  int nE = eTot < CAPE ? eTot : CAPE;                   // SGPR
  int eClamp = eBeg < GE - 1 ? eBeg : GE - 1;           // in-bounds dummy index
  // breadth-first staging: both csr chunk loads in flight, then both gathers
  int srcv[2];
#pragma unroll
  for (int c = 0; c < 2; ++c) {
    int i = c * 64 + lane;
    srcv[c] = csr[i < nE ? eBeg + i : eClamp];  // clamp keeps address valid; masked at write
  }
  uint2 pv[2];
#pragma unroll
  for (int c = 0; c < 2; ++c) pv[c] = pqb[srcv[c]];
  uint2* bw = sBuf + wv * CAPW;
#pragma unroll
  for (int c = 0; c < 2; ++c) {
    int i = c * 64 + lane;
    if (i < nE) bw[i] = pv[c];
  }
  __syncthreads();

  {
    const char* tbl16 = (const char*)sTab + l * 16;  // this lane's 4-channel column
    const char* bwB = (const char*)bw;
    float4 bb4 = ((const float4*)b2)[l];             // bias for channels 4l..4l+3

    float a0 = 0.f, a1 = 0.f, a2 = 0.f, a3 = 0.f;
    auto fdot4 = [&](uint4 t, unsigned pm) {
      half2v ph = __builtin_bit_cast(half2v, pm);
      a0 = dot2acc(__builtin_bit_cast(half2v, t.x), ph, a0);
      a1 = dot2acc(__builtin_bit_cast(half2v, t.y), ph, a1);
      a2 = dot2acc(__builtin_bit_cast(half2v, t.z), ph, a2);
      a3 = dot2acc(__builtin_bit_cast(half2v, t.w), ph, a3);
    };
    auto procM = [&](uint2 v) {  // single edge; half 1 contributes exactly 0
      unsigned pm = (h == 0) ? v.x : 0u;
      uint4 t = *(const uint4*)(tbl16 + v.y);
      fdot4(t, pm);
    };

    int sB = 0;  // SGPR: node's begin (stream-local)
    for (int d = 0; d < NPW; ++d) {
      int sE = __builtin_amdgcn_readlane(rsv, d + 1) - eBeg;  // SGPR: node's end
      a0 = 0.f; a1 = 0.f; a2 = 0.f; a3 = 0.f;
      int lim = sE < nE ? sE : nE;
      int j = sB;
      for (; j + 8 <= lim; j += 8) {  // 4 pairs in flight; scalar loop bounds
        const char* p = bwB + (size_t)(j + h) * 8;  // half h reads edges j+h, j+2+h, ...
        uint2 v0 = *(const uint2*)(p);
        uint2 v1 = *(const uint2*)(p + 16);
        uint2 v2 = *(const uint2*)(p + 32);
        uint2 v3 = *(const uint2*)(p + 48);
        uint4 t0 = *(const uint4*)(tbl16 + v0.y);
        uint4 t1 = *(const uint4*)(tbl16 + v1.y);
        uint4 t2 = *(const uint4*)(tbl16 + v2.y);
        uint4 t3 = *(const uint4*)(tbl16 + v3.y);
        fdot4(t0, v0.x);
        fdot4(t1, v1.x);
        fdot4(t2, v2.x);
        fdot4(t3, v3.x);
      }
      for (; j + 2 <= lim; j += 2) {  // pair remainder
        uint2 v = *(const uint2*)(bwB + (size_t)(j + h) * 8);
        uint4 t = *(const uint4*)(tbl16 + v.y);
        fdot4(t, v.x);
      }
      if (j < lim) procM(*(const uint2*)(bwB + (size_t)j * 8));  // odd last edge
      // overflow fallback (rows past CAPE): wave-uniform global loads; ~never taken
      for (int j2 = (sB > nE ? sB : nE); j2 < sE; ++j2) {
        int s2 = csr[eBeg + j2];
        procM(pqb[s2]);
      }
      procM(pqb[n0 + d]);  // self loop (wave-uniform load; 1 per ~80 edges)
      // cross-half reduce: halves hold disjoint edge subsets of the SAME channels
      a0 += __shfl_xor(a0, 32);
      a1 += __shfl_xor(a1, 32);
      a2 += __shfl_xor(a2, 32);
      a3 += __shfl_xor(a3, 32);
      if (h == 0) {
        float dvv = dinv[n0 + d];
        float r0 = fmaxf(fmaf(a0, dvv, bb4.x), 0.f);
        float r1 = fmaxf(fmaf(a1, dvv, bb4.y), 0.f);
        float r2 = fmaxf(fmaf(a2, dvv, bb4.z), 0.f);
        float r3 = fmaxf(fmaf(a3, dvv, bb4.w), 0.f);
        half2v o01, o23;
        o01[0] = (_Float16)r0; o01[1] = (_Float16)r1;
        o23[0] = (_Float16)r2; o23[1] = (_Float16)r3;
        uint2 ov;
        ov.x = __builtin_bit_cast(unsigned, o01);
        ov.y = __builtin_bit_cast(unsigned, o23);
        ((uint2*)h2out)[(size_t)(n0 + d) * 32 + l] = ov;  // 32 lanes x 8 B = 256 B row
      }
      sB = sE;
    }
  }

  // ---- fused GEMM: this block's 80 rows = 5 tiles; sTab reused as transposed Wc ----
  constexpr int WS = 136;
  _Float16* WtL = (_Float16*)sTab;  // 64*136*2 = 17408 B <= 66048 B
  __syncthreads();                  // main-loop writes/readers done; sTab dead
  for (int i = tid; i < GH * GOUT; i += 1024) {
    int k = i >> 6, n = i & 63;
    WtL[n * WS + k] = Wch[i];
  }
  __syncthreads();
  if (wv < 5) {  // one tile per wave; af loaded once per row, reused across col-chunks
    int m = lane & 15, q = lane >> 4;
    int row = blockIdx.x * 80 + wv * 16 + m;  // row's h2 was written by THIS block
    const _Float16* arow = h2out + (size_t)row * GH + q * 8;
    half8v af[4];
#pragma unroll
    for (int ks = 0; ks < 4; ++ks) af[ks] = *(const half8v*)(arow + ks * 32);
    floatx4 acc[4];
#pragma unroll
    for (int nt = 0; nt < 4; ++nt) {
      floatx4 z = {0.0f, 0.0f, 0.0f, 0.0f};
      acc[nt] = z;
    }
#pragma unroll
    for (int ks = 0; ks < 4; ++ks) {
#pragma unroll
      for (int nt = 0; nt < 4; ++nt) {
        half8v wf = *(const half8v*)(&WtL[(nt * 16 + m) * WS + ks * 32 + q * 8]);
        acc[nt] = __builtin_amdgcn_mfma_f32_16x16x32_f16(wf, af[ks], acc[nt], 0, 0, 0);
      }
    }
    float sc = dinv[row];
    _Float16* crow = t3out + (size_t)row * GOUT;
#pragma unroll
    for (int nt = 0; nt < 4; ++nt) {
      half4v hv;
#pragma unroll
      for (int j = 0; j < 4; ++j) hv[j] = (_Float16)(acc[nt][j] * sc);
      *(half4v*)(crow + nt * 16 + q * 4) = hv;
    }
  }
}

// ---------------- layer 3 + head: 4 nodes/wave, uint2 row segments, depth-2 prefetch ----------------

__global__ __launch_bounds__(256) void k_agg64(const _Float16* __restrict__ ht, const int* __restrict__ rowStart,
                                               const int* __restrict__ csr, const float* __restrict__ dinv,
                                               const float* __restrict__ bias, float* __restrict__ out) {
  int tid = threadIdx.x;
  int lane = tid & 63;
  int wave = (blockIdx.x << 2) + (tid >> 6);
  int g = lane >> 4;  // node slot
  int l = lane & 15;  // uint2 segment (4 channels)
  int d = (wave << 2) + g;  // 6250*4*4 = 100000 exactly
  const uint2* h2p = (const uint2*)ht;  // row = 16 uint2
  float ax = 0.f, ay = 0.f, az = 0.f, aw = 0.f;
  auto acc4 = [&](uint2 r) {
    half2v lo = __builtin_bit_cast(half2v, r.x);
    half2v hi = __builtin_bit_cast(half2v, r.y);
    ax += (float)lo[0];
    ay += (float)lo[1];
    az += (float)hi[0];
    aw += (float)hi[1];
  };
  acc4(h2p[(size_t)d * 16 + l]);  // self loop
  int e = rowStart[d];
  int en = rowStart[d + 1];
  uint2 rA0, rA1, rA2, rA3, rB0, rB1, rB2, rB3;
  bool hA = (e + 4 <= en);
  if (hA) {
    int s0 = csr[e], s1 = csr[e + 1], s2 = csr[e + 2], s3 = csr[e + 3];
    rA0 = h2p[(size_t)s0 * 16 + l]; rA1 = h2p[(size_t)s1 * 16 + l];
    rA2 = h2p[(size_t)s2 * 16 + l]; rA3 = h2p[(size_t)s3 * 16 + l];
  }
  bool hB = (e + 8 <= en);
  if (hB) {
    int s0 = csr[e + 4], s1 = csr[e + 5], s2 = csr[e + 6], s3 = csr[e + 7];
    rB0 = h2p[(size_t)s0 * 16 + l]; rB1 = h2p[(size_t)s1 * 16 + l];
    rB2 = h2p[(size_t)s2 * 16 + l]; rB3 = h2p[(size_t)s3 * 16 + l];
  }
  while (hA) {
    bool hC = (e + 12 <= en);
    uint2 rC0, rC1, rC2, rC3;
    if (hC) {
      int n0 = csr[e + 8], n1 = csr[e + 9], n2 = csr[e + 10], n3 = csr[e + 11];
      rC0 = h2p[(size_t)n0 * 16 + l]; rC1 = h2p[(size_t)n1 * 16 + l];
      rC2 = h2p[(size_t)n2 * 16 + l]; rC3 = h2p[(size_t)n3 * 16 + l];
    }
    acc4(rA0); acc4(rA1); acc4(rA2); acc4(rA3);
    rA0 = rB0; rA1 = rB1; rA2 = rB2; rA3 = rB3;
    rB0 = rC0; rB1 = rC1; rB2 = rC2; rB3 = rC3;
    e += 4;
    hA = hB;
    hB = hC;
  }
  for (; e < en; ++e) acc4(h2p[(size_t)csr[e] * 16 + l]);
  float dv = dinv[d];
  float4 bb = ((const float4*)bias)[l];
  float4 o;
  o.x = fmaf(ax, dv, bb.x);
  o.y = fmaf(ay, dv, bb.y);
  o.z = fmaf(az, dv, bb.z);
  o.w = fmaf(aw, dv, bb.w);
  ((float4*)out)[(size_t)d * 16 + l] = o;
}

// ---------------- host ----------------

extern "C" void kernel_launch(void* const* d_in, const int* in_sizes, int n_in,
                              void* d_out, int out_size, void* d_ws, size_t ws_size,
                              hipStream_t stream) {
  const float* x  = (const float*)d_in[0];
  const int*   ei = (const int*)d_in[1];
  const float* W1 = (const float*)d_in[2];
  const float* b1 = (const float*)d_in[3];
  const float* W2 = (const float*)d_in[4];
  const float* b2 = (const float*)d_in[5];
  const float* W3 = (const float*)d_in[6];
  const float* b3 = (const float*)d_in[7];
  const float* Wo = (const float*)d_in[8];
  const float* bo = (const float*)d_in[9];
  float* out = (float*)d_out;

  char* ws = (char*)d_ws;
  size_t off = 0;
  auto alloc = [&](size_t bytes) -> char* {
    off = (off + 255) & ~(size_t)255;
    char* p = ws + off;
    off += bytes;
    return p;
  };
  float*     dinv      = (float*)alloc((size_t)GN * 4);
  float*     xs        = (float*)alloc((size_t)GN * 4);
  int*       rowStart  = (int*)alloc((size_t)(GN + 1) * 4);
  int*       gCnt      = (int*)alloc((size_t)512 * 4);
  int*       csr       = (int*)alloc((size_t)GE * 4);
  unsigned*  tabS      = (unsigned*)alloc((size_t)129 * 128 * 4);  // 66 KB, bin-major
  float*     knots     = (float*)alloc((size_t)GH * 4);
  _Float16*  Wch       = (_Float16*)alloc((size_t)GH * GOUT * 2);
  float*     bch       = (float*)alloc((size_t)GOUT * 4);
  uint2*     pqb       = (uint2*)alloc((size_t)GN * 8);
  _Float16*  bufA      = (_Float16*)alloc((size_t)GN * GH * 2);   // h2 (aliases staged)
  _Float16*  bufB      = (_Float16*)alloc((size_t)GN * GOUT * 2); // t3
  unsigned*  staged    = (unsigned*)bufA;  // 7.21 MB, dead before k_exp_full writes bufA
  (void)ws_size; (void)in_sizes; (void)n_in; (void)out_size;

  // zero bucket allocators (plain dispatch; capture-safe), then merged pass1+prep:
  // edge count/place runs CONCURRENTLY with PWL table / Wch / bch generation.
  k_zero<<<1, 512, 0, stream>>>(gCnt);
  p1_prep<<<P1B + 10, 1024, 0, stream>>>(ei, gCnt, staged, W1, b1, W2, W3, Wo, b3, bo,
                                         tabS, knots, Wch, bch, rowStart);

  // CSR build (391 buckets of 256 nodes -> full-GPU grids): hist/scan -> scatter+layer1
  p2a_build<<<NBUCK, 1024, 0, stream>>>(staged, gCnt, x, dinv, xs, rowStart);
  p2b_scatter<<<NBUCK, 1024, 0, stream>>>(staged, gCnt, xs, dinv, rowStart, knots, csr, pqb);

  // layer 2 + layer-3 GEMM fused: expand (pair-split, 2 blocks/CU) then per-block MFMA
  k_exp_full<<<1250, 1024, 0, stream>>>(pqb, csr, rowStart, tabS, dinv, b2, Wch, bufA, bufB);

  // head: 4 nodes/wave uint2 aggregate -> fp32 out
  k_agg64<<<6250, 256, 0, stream>>>(bufB, rowStart, csr, dinv, bch, out);
}